// Round 2
// baseline (129.030 us; speedup 1.0000x reference)
//
#include <hip/hip_runtime.h>
#include <hip/hip_bf16.h>
#include <cstdint>

#define N_ATOMS 16384
#define PREP_THREADS 1024
#define TILE 1024

// ws layout:
//   [0,256)                 int counts[2] = {n_ctx, n_gen}
//   [256, 256+256K)         float4 ctx4[16384]  (x,y,z,xn) context atoms, ordered
//   [+256K, +512K)          float4 gen4[16384]  (x,y,z,xn) generated atoms, ordered
//   [+512K, +576K)          int genidx[16384]   original atom index of each gen atom

__global__ __launch_bounds__(PREP_THREADS)
void prep_kernel(const float* __restrict__ X,
                 const float* __restrict__ base_noise,
                 const int* __restrict__ block_ids,
                 const unsigned int* __restrict__ gen_mask_u32,  // 4096 blocks; dtype detected
                 float* __restrict__ out,
                 float4* __restrict__ ctx4,
                 float4* __restrict__ gen4,
                 int* __restrict__ genidx,
                 int* __restrict__ counts)
{
    __shared__ int wcnt_ctx[PREP_THREADS / 64];
    __shared__ int wcnt_gen[PREP_THREADS / 64];
    __shared__ int mask_is_bytes;
    const int t = threadIdx.x;
    const int wave = t >> 6;
    const int lane = t & 63;

    // --- detect mask dtype: int32 (values 0/1) vs packed bytes (bool) ---
    // First 4096 bytes are in-bounds under either interpretation.
    if (t == 0) mask_is_bytes = 0;
    __syncthreads();
    if (gen_mask_u32[t] > 1u) mask_is_bytes = 1;   // benign write race (same value)
    __syncthreads();
    const bool is_u8 = (mask_is_bytes != 0);
    const unsigned char* gen_mask_u8 = (const unsigned char*)gen_mask_u32;

    int base_ctx = 0, base_gen = 0;

    for (int iter = 0; iter < N_ATOMS / PREP_THREADS; ++iter) {
        const int i = iter * PREP_THREADS + t;
        const float x = X[3 * i + 0];
        const float y = X[3 * i + 1];
        const float z = X[3 * i + 2];
        float xn = x * x;
        xn += y * y;
        xn += z * z;
        const int bid = block_ids[i];
        const bool g = is_u8 ? (gen_mask_u8[bid] != 0) : (gen_mask_u32[bid] != 0u);

        // default output: base noise (gen atoms get overwritten by topk kernel)
        out[3 * i + 0] = base_noise[3 * i + 0];
        out[3 * i + 1] = base_noise[3 * i + 1];
        out[3 * i + 2] = base_noise[3 * i + 2];

        const unsigned long long mc = __ballot(!g);
        const unsigned long long mg = __ballot(g);
        if (lane == 0) {
            wcnt_ctx[wave] = __popcll(mc);
            wcnt_gen[wave] = __popcll(mg);
        }
        __syncthreads();
        int oc = base_ctx, og = base_gen;
        #pragma unroll
        for (int w = 0; w < PREP_THREADS / 64; ++w) {
            const int cc = wcnt_ctx[w];
            const int cg = wcnt_gen[w];
            if (w < wave) { oc += cc; og += cg; }
            base_ctx += cc;
            base_gen += cg;
        }
        const unsigned long long below = (1ull << lane) - 1ull;
        oc += __popcll(mc & below);
        og += __popcll(mg & below);
        if (!g) {
            ctx4[oc] = make_float4(x, y, z, xn);
        } else {
            gen4[og] = make_float4(x, y, z, xn);
            genidx[og] = i;
        }
        __syncthreads();
    }
    if (t == 0) {
        counts[0] = base_ctx;
        counts[1] = base_gen;
    }
}

__global__ __launch_bounds__(256)
void topk_kernel(const float4* __restrict__ ctx4,
                 const float4* __restrict__ gen4,
                 const int* __restrict__ genidx,
                 const int* __restrict__ counts,
                 const float* __restrict__ cnoise,
                 float* __restrict__ out)
{
    const int n_gen = counts[1];
    if ((int)blockIdx.x * 32 >= n_gen) return;
    const int n_ctx = counts[0];

    const int t = threadIdx.x;
    const int slot = blockIdx.x * 32 + (t >> 3);   // which gen atom
    const int slice = t & 7;                       // candidate stream slice
    const bool valid = slot < n_gen;
    const int sload = valid ? slot : 0;

    const float4 me = gen4[sload];
    const float xi = me.x, yi = me.y, zi = me.z, xni = me.w;

    __shared__ float4 tile[TILE];

    float s1 = INFINITY, s2 = INFINITY, s3 = INFINITY;
    int i1 = 0, i2 = 0, i3 = 0;

    for (int tb = 0; tb < n_ctx; tb += TILE) {
        const int nt = min(TILE, n_ctx - tb);
        __syncthreads();
        for (int r = t; r < nt; r += 256) tile[r] = ctx4[tb + r];
        __syncthreads();
        #pragma unroll 4
        for (int j = slice; j < nt; j += 8) {
            const float4 c = tile[j];
            const float dot = xi * c.x + yi * c.y + zi * c.z;
            const float sq = (xni + c.w) - 2.0f * dot;
            if (sq < s3) {
                const bool b1 = sq < s1, b2 = sq < s2;
                const int idx = tb + j;
                i3 = b2 ? i2 : idx;
                s3 = b2 ? s2 : sq;
                i2 = b1 ? i1 : (b2 ? idx : i2);
                s2 = b1 ? s1 : (b2 ? sq : s2);
                i1 = b1 ? idx : i1;
                s1 = b1 ? sq : s1;
            }
        }
    }

    // butterfly merge of sorted triples across the 8 slices of this atom
    #pragma unroll
    for (int m = 1; m <= 4; m <<= 1) {
        const float oa = __shfl_xor(s1, m); const int ja = __shfl_xor(i1, m);
        const float ob = __shfl_xor(s2, m); const int jb = __shfl_xor(i2, m);
        const float oc = __shfl_xor(s3, m); const int jc = __shfl_xor(i3, m);
        {
            const bool b1 = oa < s1, b2 = oa < s2, b3 = oa < s3;
            s3 = b2 ? s2 : (b3 ? oa : s3); i3 = b2 ? i2 : (b3 ? ja : i3);
            s2 = b1 ? s1 : (b2 ? oa : s2); i2 = b1 ? i1 : (b2 ? ja : i2);
            s1 = b1 ? oa : s1;             i1 = b1 ? ja : i1;
        }
        {
            const bool b1 = ob < s1, b2 = ob < s2, b3 = ob < s3;
            s3 = b2 ? s2 : (b3 ? ob : s3); i3 = b2 ? i2 : (b3 ? jb : i3);
            s2 = b1 ? s1 : (b2 ? ob : s2); i2 = b1 ? i1 : (b2 ? jb : i2);
            s1 = b1 ? ob : s1;             i1 = b1 ? jb : i1;
        }
        {
            const bool b1 = oc < s1, b2 = oc < s2, b3 = oc < s3;
            s3 = b2 ? s2 : (b3 ? oc : s3); i3 = b2 ? i2 : (b3 ? jc : i3);
            s2 = b1 ? s1 : (b2 ? oc : s2); i2 = b1 ? i1 : (b2 ? jc : i2);
            s1 = b1 ? oc : s1;             i1 = b1 ? jc : i1;
        }
    }

    if (valid && slice == 0) {
        const float d1 = sqrtf(fmaxf(s1, 0.0f) + 1e-12f);
        const float d2 = sqrtf(fmaxf(s2, 0.0f) + 1e-12f);
        const float d3 = sqrtf(fmaxf(s3, 0.0f) + 1e-12f);
        float w1 = 1.0f / (d1 + 1e-8f);
        float w2 = 1.0f / (d2 + 1e-8f);
        float w3 = 1.0f / (d3 + 1e-8f);
        float wsum = w1 + w2;
        wsum += w3;
        w1 /= wsum; w2 /= wsum; w3 /= wsum;
        const float4 c1 = ctx4[i1];
        const float4 c2 = ctx4[i2];
        const float4 c3 = ctx4[i3];
        const int ai = genidx[slot];
        float cx = w1 * c1.x + w2 * c2.x; cx += w3 * c3.x;
        float cy = w1 * c1.y + w2 * c2.y; cy += w3 * c3.y;
        float cz = w1 * c1.z + w2 * c2.z; cz += w3 * c3.z;
        out[3 * ai + 0] = cx + 0.5f * cnoise[3 * ai + 0];
        out[3 * ai + 1] = cy + 0.5f * cnoise[3 * ai + 1];
        out[3 * ai + 2] = cz + 0.5f * cnoise[3 * ai + 2];
    }
}

extern "C" void kernel_launch(void* const* d_in, const int* in_sizes, int n_in,
                              void* d_out, int out_size, void* d_ws, size_t ws_size,
                              hipStream_t stream) {
    const float* X          = (const float*)d_in[0];
    const float* base_noise = (const float*)d_in[1];
    const float* cnoise     = (const float*)d_in[2];
    const int*   block_ids  = (const int*)d_in[3];
    const unsigned int* gmask = (const unsigned int*)d_in[4];
    float* out = (float*)d_out;

    char* ws = (char*)d_ws;
    int*    counts = (int*)(ws + 0);
    float4* ctx4   = (float4*)(ws + 256);
    float4* gen4   = (float4*)(ws + 256 + 262144);
    int*    genidx = (int*)(ws + 256 + 2 * 262144);

    prep_kernel<<<1, PREP_THREADS, 0, stream>>>(X, base_noise, block_ids, gmask,
                                                out, ctx4, gen4, genidx, counts);
    topk_kernel<<<512, 256, 0, stream>>>(ctx4, gen4, genidx, counts, cnoise, out);
}

// Round 3
// 95.456 us; speedup vs baseline: 1.3517x; 1.3517x over previous
//
#include <hip/hip_runtime.h>
#include <hip/hip_bf16.h>
#include <cstdint>

#define N_ATOMS 16384
#define PBLK 64        // prep grid
#define PTHR 256       // prep block size
#define TILE 1024      // ctx float4 per LDS tile (16 KB)
#define AT 4           // atoms per wave in topk

// ws layout:
//   [0,64)        int counts[2]: {n_ctx, n_gen}
//   [256,512)     int blk_gen[64]   per-prep-block gen counts
//   [512,768)     int blk_goff[64]  exclusive prefix of blk_gen
//   [1024, +256K) float4 ctx4[16384] (x,y,z,|x|^2) context atoms, original order
//   [+256K]       float4 gen4[16384] generated atoms, original order
//   [+512K]       int genidx[16384]  original atom index per gen slot

__device__ __forceinline__ bool detect_u8_mask(const unsigned int* m, int t, int* sflag) {
    // generate_mask dtype probe: int32 0/1 values vs packed bool bytes.
    // First 1024 bytes valid under either layout. P(false negative) ~ 8^-256.
    if (t == 0) *sflag = 0;
    __syncthreads();
    if (t < 256 && m[t] > 1u) *sflag = 1;   // benign same-value race
    __syncthreads();
    return *sflag != 0;
}

__device__ __forceinline__ bool gen_flag(const unsigned int* m32, bool is_u8, int bid) {
    const unsigned char* m8 = (const unsigned char*)m32;
    return is_u8 ? (m8[bid] != 0) : (m32[bid] != 0u);
}

__global__ __launch_bounds__(PTHR)
void count_kernel(const int* __restrict__ block_ids,
                  const unsigned int* __restrict__ mask,
                  int* __restrict__ blk_gen)
{
    __shared__ int sflag;
    __shared__ int wg[PTHR / 64];
    const int t = threadIdx.x;
    const bool is_u8 = detect_u8_mask(mask, t, &sflag);
    const int i = blockIdx.x * PTHR + t;
    const bool g = gen_flag(mask, is_u8, block_ids[i]);
    const unsigned long long mg = __ballot(g);
    if ((t & 63) == 0) wg[t >> 6] = __popcll(mg);
    __syncthreads();
    if (t == 0) blk_gen[blockIdx.x] = wg[0] + wg[1] + wg[2] + wg[3];
}

__global__ __launch_bounds__(64)
void scan_kernel(const int* __restrict__ blk_gen,
                 int* __restrict__ blk_goff,
                 int* __restrict__ counts)
{
    const int lane = threadIdx.x;
    const int orig = blk_gen[lane];
    int v = orig;
    #pragma unroll
    for (int d = 1; d < 64; d <<= 1) {
        const int u = __shfl_up(v, d);
        if (lane >= d) v += u;
    }
    blk_goff[lane] = v - orig;   // exclusive prefix
    if (lane == 63) {
        counts[1] = v;            // n_gen
        counts[0] = N_ATOMS - v;  // n_ctx
    }
}

__global__ __launch_bounds__(PTHR)
void compact_kernel(const float* __restrict__ X,
                    const float* __restrict__ base_noise,
                    const int* __restrict__ block_ids,
                    const unsigned int* __restrict__ mask,
                    const int* __restrict__ blk_goff,
                    float* __restrict__ out,
                    float4* __restrict__ ctx4,
                    float4* __restrict__ gen4,
                    int* __restrict__ genidx)
{
    __shared__ int sflag;
    __shared__ int wg[PTHR / 64];
    __shared__ int wc[PTHR / 64];
    const int t = threadIdx.x;
    const int wave = t >> 6;
    const int lane = t & 63;
    const bool is_u8 = detect_u8_mask(mask, t, &sflag);

    const int i = blockIdx.x * PTHR + t;
    const float x = X[3 * i + 0];
    const float y = X[3 * i + 1];
    const float z = X[3 * i + 2];
    float xn = x * x;
    xn += y * y;
    xn += z * z;
    const bool g = gen_flag(mask, is_u8, block_ids[i]);

    // default output (gen atoms overwritten by topk)
    out[3 * i + 0] = base_noise[3 * i + 0];
    out[3 * i + 1] = base_noise[3 * i + 1];
    out[3 * i + 2] = base_noise[3 * i + 2];

    const unsigned long long mg = __ballot(g);
    const unsigned long long mc = __ballot(!g);
    if (lane == 0) { wg[wave] = __popcll(mg); wc[wave] = __popcll(mc); }
    __syncthreads();

    const int gbase_blk = blk_goff[blockIdx.x];
    const int cbase_blk = blockIdx.x * PTHR - gbase_blk;
    int og = gbase_blk, oc = cbase_blk;
    #pragma unroll
    for (int w = 0; w < PTHR / 64; ++w) {
        if (w < wave) { og += wg[w]; oc += wc[w]; }
    }
    const unsigned long long below = (1ull << lane) - 1ull;
    og += __popcll(mg & below);
    oc += __popcll(mc & below);

    if (!g) {
        ctx4[oc] = make_float4(x, y, z, xn);
    } else {
        gen4[og] = make_float4(x, y, z, xn);
        genidx[og] = i;
    }
}

__device__ __forceinline__ void ins3(float v, int vi,
                                     float& s1, float& s2, float& s3,
                                     int& i1, int& i2, int& i3)
{
    const bool b1 = v < s1, b2 = v < s2, b3 = v < s3;
    s3 = b2 ? s2 : (b3 ? v : s3);   i3 = b2 ? i2 : (b3 ? vi : i3);
    s2 = b1 ? s1 : (b2 ? v : s2);   i2 = b1 ? i1 : (b2 ? vi : i2);
    s1 = b1 ? v : s1;               i1 = b1 ? vi : i1;
}

__global__ __launch_bounds__(256)
void topk_kernel(const float4* __restrict__ ctx4,
                 const float4* __restrict__ gen4,
                 const int* __restrict__ genidx,
                 const int* __restrict__ counts,
                 const float* __restrict__ cnoise,
                 float* __restrict__ out)
{
    const int n_gen = counts[1];
    const int blk_base = (int)blockIdx.x * (AT * 4);
    if (blk_base >= n_gen) return;
    const int n_ctx = counts[0];

    const int t = threadIdx.x;
    const int wave = t >> 6;
    const int lane = t & 63;
    const int abase = blk_base + wave * AT;   // first atom of this wave

    float xi[AT], yi[AT], zi[AT], xn[AT];
    float s1[AT], s2[AT], s3[AT];
    int   i1[AT], i2[AT], i3[AT];
    #pragma unroll
    for (int k = 0; k < AT; ++k) {
        int slot = abase + k;
        slot = slot < n_gen ? slot : 0;       // clamp; write suppressed later
        const float4 a = gen4[slot];
        xi[k] = a.x; yi[k] = a.y; zi[k] = a.z; xn[k] = a.w;
        s1[k] = INFINITY; s2[k] = INFINITY; s3[k] = INFINITY;
        i1[k] = 0; i2[k] = 0; i3[k] = 0;
    }

    __shared__ float4 tile[TILE];

    for (int tb = 0; tb < n_ctx; tb += TILE) {
        const int nt = min(TILE, n_ctx - tb);
        __syncthreads();
        for (int r = t; r < nt; r += 256) tile[r] = ctx4[tb + r];
        __syncthreads();
        for (int j = lane; j < nt; j += 64) {
            const float4 c = tile[j];
            const int idx = tb + j;
            #pragma unroll
            for (int k = 0; k < AT; ++k) {
                const float dot = xi[k] * c.x + yi[k] * c.y + zi[k] * c.z;
                const float sq = (xn[k] + c.w) - 2.0f * dot;
                ins3(sq, idx, s1[k], s2[k], s3[k], i1[k], i2[k], i3[k]);
            }
        }
    }

    // 6-level butterfly merge of per-lane sorted triples across the wave
    #pragma unroll
    for (int m = 1; m < 64; m <<= 1) {
        #pragma unroll
        for (int k = 0; k < AT; ++k) {
            const float oa = __shfl_xor(s1[k], m); const int ja = __shfl_xor(i1[k], m);
            const float ob = __shfl_xor(s2[k], m); const int jb = __shfl_xor(i2[k], m);
            const float oc = __shfl_xor(s3[k], m); const int jc = __shfl_xor(i3[k], m);
            ins3(oa, ja, s1[k], s2[k], s3[k], i1[k], i2[k], i3[k]);
            ins3(ob, jb, s1[k], s2[k], s3[k], i1[k], i2[k], i3[k]);
            ins3(oc, jc, s1[k], s2[k], s3[k], i1[k], i2[k], i3[k]);
        }
    }

    if (lane == 0) {
        #pragma unroll
        for (int k = 0; k < AT; ++k) {
            const int slot = abase + k;
            if (slot < n_gen) {
                const float d1 = sqrtf(fmaxf(s1[k], 0.0f) + 1e-12f);
                const float d2 = sqrtf(fmaxf(s2[k], 0.0f) + 1e-12f);
                const float d3 = sqrtf(fmaxf(s3[k], 0.0f) + 1e-12f);
                float w1 = 1.0f / (d1 + 1e-8f);
                float w2 = 1.0f / (d2 + 1e-8f);
                float w3 = 1.0f / (d3 + 1e-8f);
                float wsum = w1 + w2;
                wsum += w3;
                w1 /= wsum; w2 /= wsum; w3 /= wsum;
                const float4 c1 = ctx4[i1[k]];
                const float4 c2 = ctx4[i2[k]];
                const float4 c3 = ctx4[i3[k]];
                const int ai = genidx[slot];
                float cx = w1 * c1.x + w2 * c2.x; cx += w3 * c3.x;
                float cy = w1 * c1.y + w2 * c2.y; cy += w3 * c3.y;
                float cz = w1 * c1.z + w2 * c2.z; cz += w3 * c3.z;
                out[3 * ai + 0] = cx + 0.5f * cnoise[3 * ai + 0];
                out[3 * ai + 1] = cy + 0.5f * cnoise[3 * ai + 1];
                out[3 * ai + 2] = cz + 0.5f * cnoise[3 * ai + 2];
            }
        }
    }
}

extern "C" void kernel_launch(void* const* d_in, const int* in_sizes, int n_in,
                              void* d_out, int out_size, void* d_ws, size_t ws_size,
                              hipStream_t stream) {
    const float* X          = (const float*)d_in[0];
    const float* base_noise = (const float*)d_in[1];
    const float* cnoise     = (const float*)d_in[2];
    const int*   block_ids  = (const int*)d_in[3];
    const unsigned int* gmask = (const unsigned int*)d_in[4];
    float* out = (float*)d_out;

    char* ws = (char*)d_ws;
    int*    counts   = (int*)(ws + 0);
    int*    blk_gen  = (int*)(ws + 256);
    int*    blk_goff = (int*)(ws + 512);
    float4* ctx4     = (float4*)(ws + 1024);
    float4* gen4     = (float4*)(ws + 1024 + 262144);
    int*    genidx   = (int*)(ws + 1024 + 2 * 262144);

    count_kernel<<<PBLK, PTHR, 0, stream>>>(block_ids, gmask, blk_gen);
    scan_kernel<<<1, 64, 0, stream>>>(blk_gen, blk_goff, counts);
    compact_kernel<<<PBLK, PTHR, 0, stream>>>(X, base_noise, block_ids, gmask,
                                              blk_goff, out, ctx4, gen4, genidx);
    topk_kernel<<<N_ATOMS / (AT * 4), 256, 0, stream>>>(ctx4, gen4, genidx,
                                                        counts, cnoise, out);
}

// Round 4
// 69.917 us; speedup vs baseline: 1.8455x; 1.3653x over previous
//
#include <hip/hip_runtime.h>
#include <hip/hip_bf16.h>
#include <cstdint>

#define N_ATOMS 16384
#define PBLK 64        // prep grid
#define PTHR 256       // prep block size
#define TILE 1024      // ctx float4 per LDS tile (16 KB)
#define AT 4           // atoms per wave in topk
#define TPB 512        // topk threads per block (8 waves)
#define SINIT 3.0e38f  // top-3 init score
#define SPAD  3.38e38f // pad sentinel |x|^2 (> SINIT after adds, never inserted)

// ws layout:
//   [0,64)        int counts[2]: {n_ctx, n_gen}
//   [256,512)     int blk_gen[64]   per-prep-block gen counts
//   [512,768)     int blk_goff[64]  exclusive prefix of blk_gen
//   [1024, +256K) float4 ctx4[16384] (x,y,z,|x|^2), original order, tile-padded
//   [+256K]       float4 gen4[16384]
//   [+512K]       int genidx[16384]

__device__ __forceinline__ bool detect_u8_mask(const unsigned int* m, int t, int* sflag) {
    // generate_mask dtype probe: int32 0/1 values vs packed bool bytes.
    if (t == 0) *sflag = 0;
    __syncthreads();
    if (t < 256 && m[t] > 1u) *sflag = 1;   // benign same-value race
    __syncthreads();
    return *sflag != 0;
}

__device__ __forceinline__ bool gen_flag(const unsigned int* m32, bool is_u8, int bid) {
    const unsigned char* m8 = (const unsigned char*)m32;
    return is_u8 ? (m8[bid] != 0) : (m32[bid] != 0u);
}

__global__ __launch_bounds__(PTHR)
void count_kernel(const int* __restrict__ block_ids,
                  const unsigned int* __restrict__ mask,
                  int* __restrict__ blk_gen)
{
    __shared__ int sflag;
    __shared__ int wg[PTHR / 64];
    const int t = threadIdx.x;
    const bool is_u8 = detect_u8_mask(mask, t, &sflag);
    const int i = blockIdx.x * PTHR + t;
    const bool g = gen_flag(mask, is_u8, block_ids[i]);
    const unsigned long long mg = __ballot(g);
    if ((t & 63) == 0) wg[t >> 6] = __popcll(mg);
    __syncthreads();
    if (t == 0) blk_gen[blockIdx.x] = wg[0] + wg[1] + wg[2] + wg[3];
}

__global__ __launch_bounds__(64)
void scan_kernel(const int* __restrict__ blk_gen,
                 int* __restrict__ blk_goff,
                 int* __restrict__ counts,
                 float4* __restrict__ ctx4)
{
    const int lane = threadIdx.x;
    const int orig = blk_gen[lane];
    int v = orig;
    #pragma unroll
    for (int d = 1; d < 64; d <<= 1) {
        const int u = __shfl_up(v, d);
        if (lane >= d) v += u;
    }
    blk_goff[lane] = v - orig;   // exclusive prefix
    const int n_gen = __shfl(v, 63);
    const int n_ctx = N_ATOMS - n_gen;
    if (lane == 63) {
        counts[1] = n_gen;
        counts[0] = n_ctx;
    }
    // pad ctx4 to a TILE multiple with never-selected sentinels
    const int padded = ((n_ctx + TILE - 1) / TILE) * TILE;
    for (int p = n_ctx + lane; p < padded; p += 64)
        ctx4[p] = make_float4(0.0f, 0.0f, 0.0f, SPAD);
}

__global__ __launch_bounds__(PTHR)
void compact_kernel(const float* __restrict__ X,
                    const float* __restrict__ base_noise,
                    const int* __restrict__ block_ids,
                    const unsigned int* __restrict__ mask,
                    const int* __restrict__ blk_goff,
                    float* __restrict__ out,
                    float4* __restrict__ ctx4,
                    float4* __restrict__ gen4,
                    int* __restrict__ genidx)
{
    __shared__ int sflag;
    __shared__ int wg[PTHR / 64];
    __shared__ int wc[PTHR / 64];
    const int t = threadIdx.x;
    const int wave = t >> 6;
    const int lane = t & 63;
    const bool is_u8 = detect_u8_mask(mask, t, &sflag);

    const int i = blockIdx.x * PTHR + t;
    const float x = X[3 * i + 0];
    const float y = X[3 * i + 1];
    const float z = X[3 * i + 2];
    float xn = x * x;
    xn += y * y;
    xn += z * z;
    const bool g = gen_flag(mask, is_u8, block_ids[i]);

    out[3 * i + 0] = base_noise[3 * i + 0];
    out[3 * i + 1] = base_noise[3 * i + 1];
    out[3 * i + 2] = base_noise[3 * i + 2];

    const unsigned long long mg = __ballot(g);
    const unsigned long long mc = __ballot(!g);
    if (lane == 0) { wg[wave] = __popcll(mg); wc[wave] = __popcll(mc); }
    __syncthreads();

    const int gbase_blk = blk_goff[blockIdx.x];
    const int cbase_blk = blockIdx.x * PTHR - gbase_blk;
    int og = gbase_blk, oc = cbase_blk;
    #pragma unroll
    for (int w = 0; w < PTHR / 64; ++w) {
        if (w < wave) { og += wg[w]; oc += wc[w]; }
    }
    const unsigned long long below = (1ull << lane) - 1ull;
    og += __popcll(mg & below);
    oc += __popcll(mc & below);

    if (!g) {
        ctx4[oc] = make_float4(x, y, z, xn);
    } else {
        gen4[og] = make_float4(x, y, z, xn);
        genidx[og] = i;
    }
}

__device__ __forceinline__ void ins3(float v, int vi,
                                     float& s1, float& s2, float& s3,
                                     int& i1, int& i2, int& i3)
{
    const bool b1 = v < s1, b2 = v < s2, b3 = v < s3;
    s3 = b2 ? s2 : (b3 ? v : s3);   i3 = b2 ? i2 : (b3 ? vi : i3);
    s2 = b1 ? s1 : (b2 ? v : s2);   i2 = b1 ? i1 : (b2 ? vi : i2);
    s1 = b1 ? v : s1;               i1 = b1 ? vi : i1;
}

__global__ __launch_bounds__(TPB)
void topk_kernel(const float4* __restrict__ ctx4,
                 const float4* __restrict__ gen4,
                 const int* __restrict__ genidx,
                 const int* __restrict__ counts,
                 const float* __restrict__ cnoise,
                 float* __restrict__ out)
{
    const int n_gen = counts[1];
    const int blk_base = (int)blockIdx.x * 16;    // 16 atoms per block
    if (blk_base >= n_gen) return;
    const int n_ctx = counts[0];
    const int T  = (n_ctx + TILE - 1) / TILE;     // padded tile count
    const int H0 = (T + 1) >> 1;                  // tiles for half 0
    const int H1 = T >> 1;                        // tiles for half 1

    const int t = threadIdx.x;
    const int wave = t >> 6;
    const int lane = t & 63;
    const int grp  = wave & 3;                    // atom group (4 atoms each)
    const int half = wave >> 2;                   // ctx half
    const int abase = blk_base + grp * AT;

    float xi[AT], yi[AT], zi[AT], xn[AT];
    float s1[AT], s2[AT], s3[AT];
    int   i1[AT], i2[AT], i3[AT];
    #pragma unroll
    for (int k = 0; k < AT; ++k) {
        int slot = abase + k;
        slot = slot < n_gen ? slot : 0;
        const float4 a = gen4[slot];
        xi[k] = a.x; yi[k] = a.y; zi[k] = a.z; xn[k] = a.w;
        s1[k] = SINIT; s2[k] = SINIT; s3[k] = SINIT;
        i1[k] = 0; i2[k] = 0; i3[k] = 0;
    }

    __shared__ float4 ldsA[TILE];
    __shared__ float4 ldsB[TILE];

    for (int it = 0; it < H0; ++it) {
        __syncthreads();
        {
            const float4* srcA = ctx4 + (size_t)it * TILE;
            ldsA[t]       = srcA[t];
            ldsA[t + 512] = srcA[t + 512];
            if (it < H1) {
                const float4* srcB = ctx4 + (size_t)(H0 + it) * TILE;
                ldsB[t]       = srcB[t];
                ldsB[t + 512] = srcB[t + 512];
            }
        }
        __syncthreads();
        if (half == 0 || it < H1) {
            const float4* tl = half ? ldsB : ldsA;
            const int tbase = (half ? (H0 + it) : it) * TILE;
            #pragma unroll 8
            for (int jj = 0; jj < TILE / 64; ++jj) {
                const float4 c = tl[jj * 64 + lane];
                const int idx = tbase + jj * 64 + lane;
                #pragma unroll
                for (int k = 0; k < AT; ++k) {
                    const float dot = xi[k] * c.x + yi[k] * c.y + zi[k] * c.z;
                    const float sq = (xn[k] + c.w) - 2.0f * dot;
                    ins3(sq, idx, s1[k], s2[k], s3[k], i1[k], i2[k], i3[k]);
                }
            }
        }
    }

    // 6-level butterfly merge of per-lane sorted triples across each wave
    #pragma unroll
    for (int m = 1; m < 64; m <<= 1) {
        #pragma unroll
        for (int k = 0; k < AT; ++k) {
            const float oa = __shfl_xor(s1[k], m); const int ja = __shfl_xor(i1[k], m);
            const float ob = __shfl_xor(s2[k], m); const int jb = __shfl_xor(i2[k], m);
            const float oc = __shfl_xor(s3[k], m); const int jc = __shfl_xor(i3[k], m);
            ins3(oa, ja, s1[k], s2[k], s3[k], i1[k], i2[k], i3[k]);
            ins3(ob, jb, s1[k], s2[k], s3[k], i1[k], i2[k], i3[k]);
            ins3(oc, jc, s1[k], s2[k], s3[k], i1[k], i2[k], i3[k]);
        }
    }

    // cross-half merge through LDS (16 atoms x 6 words), then epilogue
    __syncthreads();
    int* mrg = (int*)ldsA;
    if (half == 1 && lane == 0) {
        #pragma unroll
        for (int k = 0; k < AT; ++k) {
            const int b = (grp * AT + k) * 6;
            mrg[b + 0] = __float_as_int(s1[k]);
            mrg[b + 1] = __float_as_int(s2[k]);
            mrg[b + 2] = __float_as_int(s3[k]);
            mrg[b + 3] = i1[k];
            mrg[b + 4] = i2[k];
            mrg[b + 5] = i3[k];
        }
    }
    __syncthreads();
    if (half == 0 && lane == 0) {
        #pragma unroll
        for (int k = 0; k < AT; ++k) {
            const int b = (grp * AT + k) * 6;
            const float oa = __int_as_float(mrg[b + 0]); const int ja = mrg[b + 3];
            const float ob = __int_as_float(mrg[b + 1]); const int jb = mrg[b + 4];
            const float oc = __int_as_float(mrg[b + 2]); const int jc = mrg[b + 5];
            ins3(oa, ja, s1[k], s2[k], s3[k], i1[k], i2[k], i3[k]);
            ins3(ob, jb, s1[k], s2[k], s3[k], i1[k], i2[k], i3[k]);
            ins3(oc, jc, s1[k], s2[k], s3[k], i1[k], i2[k], i3[k]);

            const int slot = abase + k;
            if (slot < n_gen) {
                const float d1 = sqrtf(fmaxf(s1[k], 0.0f) + 1e-12f);
                const float d2 = sqrtf(fmaxf(s2[k], 0.0f) + 1e-12f);
                const float d3 = sqrtf(fmaxf(s3[k], 0.0f) + 1e-12f);
                float w1 = 1.0f / (d1 + 1e-8f);
                float w2 = 1.0f / (d2 + 1e-8f);
                float w3 = 1.0f / (d3 + 1e-8f);
                float wsum = w1 + w2;
                wsum += w3;
                w1 /= wsum; w2 /= wsum; w3 /= wsum;
                const float4 c1 = ctx4[i1[k]];
                const float4 c2 = ctx4[i2[k]];
                const float4 c3 = ctx4[i3[k]];
                const int ai = genidx[slot];
                float cx = w1 * c1.x + w2 * c2.x; cx += w3 * c3.x;
                float cy = w1 * c1.y + w2 * c2.y; cy += w3 * c3.y;
                float cz = w1 * c1.z + w2 * c2.z; cz += w3 * c3.z;
                out[3 * ai + 0] = cx + 0.5f * cnoise[3 * ai + 0];
                out[3 * ai + 1] = cy + 0.5f * cnoise[3 * ai + 1];
                out[3 * ai + 2] = cz + 0.5f * cnoise[3 * ai + 2];
            }
        }
    }
}

extern "C" void kernel_launch(void* const* d_in, const int* in_sizes, int n_in,
                              void* d_out, int out_size, void* d_ws, size_t ws_size,
                              hipStream_t stream) {
    const float* X          = (const float*)d_in[0];
    const float* base_noise = (const float*)d_in[1];
    const float* cnoise     = (const float*)d_in[2];
    const int*   block_ids  = (const int*)d_in[3];
    const unsigned int* gmask = (const unsigned int*)d_in[4];
    float* out = (float*)d_out;

    char* ws = (char*)d_ws;
    int*    counts   = (int*)(ws + 0);
    int*    blk_gen  = (int*)(ws + 256);
    int*    blk_goff = (int*)(ws + 512);
    float4* ctx4     = (float4*)(ws + 1024);
    float4* gen4     = (float4*)(ws + 1024 + 262144);
    int*    genidx   = (int*)(ws + 1024 + 2 * 262144);

    count_kernel<<<PBLK, PTHR, 0, stream>>>(block_ids, gmask, blk_gen);
    scan_kernel<<<1, 64, 0, stream>>>(blk_gen, blk_goff, counts, ctx4);
    compact_kernel<<<PBLK, PTHR, 0, stream>>>(X, base_noise, block_ids, gmask,
                                              blk_goff, out, ctx4, gen4, genidx);
    topk_kernel<<<N_ATOMS / 16, TPB, 0, stream>>>(ctx4, gen4, genidx,
                                                  counts, cnoise, out);
}

// Round 5
// 52.358 us; speedup vs baseline: 2.4644x; 1.3354x over previous
//
#include <hip/hip_runtime.h>
#include <cstdint>

#define N_ATOMS 16384
#define NBLK 64
#define NTHR 256
#define G 24
#define NCELLS (G*G*G)            // 13824
#define NCELLS_PAD 14336          // 1024*14
#define CPT 14                    // cells per thread in K2 scan
#define BOX_LO -48.0f
#define INV_CELL 0.25f            // cell side 4.0
#define SINIT 3.0e38f

// ws layout (total 445,696 B < 590KB proven safe):
#define OFF_COUNTS 0              // int[2]: n_ctx, n_gen
#define OFF_BLKGEN 256            // int[64]
#define OFF_BLKGOFF 512           // int[64]
#define OFF_FLAGS 1024            // u64[256] gen bit per atom
#define OFF_CNT 3072              // int[14336] cell counts -> cursors
#define OFF_START 60416           // int[14337] cell starts
#define OFF_GENIDX 118016         // int[16384]
#define OFF_CTX4 183552           // float4[16384] cell-sorted (x,y,z,|x|^2)

__device__ __forceinline__ int cell1(float x) {
    int c = (int)floorf((x - BOX_LO) * INV_CELL);
    return min(max(c, 0), G - 1);
}

__device__ __forceinline__ void ins3(float v, int vi,
                                     float& s1, float& s2, float& s3,
                                     int& i1, int& i2, int& i3)
{
    const bool b1 = v < s1, b2 = v < s2, b3 = v < s3;
    s3 = b2 ? s2 : (b3 ? v : s3);   i3 = b2 ? i2 : (b3 ? vi : i3);
    s2 = b1 ? s1 : (b2 ? v : s2);   i2 = b1 ? i1 : (b2 ? vi : i2);
    s1 = b1 ? v : s1;               i1 = b1 ? vi : i1;
}

__device__ __forceinline__ void ins3v(float v, float& s1, float& s2, float& s3)
{
    const bool b1 = v < s1, b2 = v < s2, b3 = v < s3;
    s3 = b2 ? s2 : (b3 ? v : s3);
    s2 = b1 ? s1 : (b2 ? v : s2);
    s1 = b1 ? v : s1;
}

__global__ __launch_bounds__(NTHR)
void k1_classify(const float* __restrict__ X,
                 const int* __restrict__ block_ids,
                 const unsigned int* __restrict__ mask,
                 const float* __restrict__ base_noise,
                 float* __restrict__ out,
                 unsigned long long* __restrict__ flags,
                 int* __restrict__ blk_gen,
                 int* __restrict__ cell_cnt)
{
    __shared__ int sflag;
    __shared__ int wg[4];
    const int t = threadIdx.x;
    const int wave = t >> 6, lane = t & 63;

    // mask dtype probe: int32 0/1 values vs packed bool bytes (as R2-R4, validated)
    if (t == 0) sflag = 0;
    __syncthreads();
    if (mask[t] > 1u) sflag = 1;    // benign same-value race
    __syncthreads();
    const bool is_u8 = (sflag != 0);
    const unsigned char* m8 = (const unsigned char*)mask;

    const int i = blockIdx.x * NTHR + t;
    const int bid = block_ids[i];
    const bool g = is_u8 ? (m8[bid] != 0) : (mask[bid] != 0u);

    out[3 * i + 0] = base_noise[3 * i + 0];
    out[3 * i + 1] = base_noise[3 * i + 1];
    out[3 * i + 2] = base_noise[3 * i + 2];

    const unsigned long long mg = __ballot(g);
    if (lane == 0) { flags[blockIdx.x * 4 + wave] = mg; wg[wave] = __popcll(mg); }
    __syncthreads();
    if (t == 0) blk_gen[blockIdx.x] = wg[0] + wg[1] + wg[2] + wg[3];

    if (!g) {
        const float x = X[3 * i], y = X[3 * i + 1], z = X[3 * i + 2];
        const int cx = cell1(x), cy = cell1(y), cz = cell1(z);
        atomicAdd(&cell_cnt[(cz * G + cy) * G + cx], 1);
    }
}

__global__ __launch_bounds__(1024)
void k2_scan(int* __restrict__ cell_cnt,
             int* __restrict__ cell_start,
             const int* __restrict__ blk_gen,
             int* __restrict__ blk_goff,
             int* __restrict__ counts)
{
    const int t = threadIdx.x;
    const int wave = t >> 6, lane = t & 63;
    int loc[CPT]; int sum = 0;
    #pragma unroll
    for (int k = 0; k < CPT; ++k) {
        const int v = cell_cnt[t * CPT + k];
        loc[k] = sum; sum += v;
    }
    int v = sum;
    #pragma unroll
    for (int d = 1; d < 64; d <<= 1) { const int u = __shfl_up(v, d); if (lane >= d) v += u; }
    __shared__ int wsum[16], wexc[16];
    if (lane == 63) wsum[wave] = v;
    __syncthreads();
    if (t < 16) {
        int v2 = wsum[t];
        const int orig = v2;
        #pragma unroll
        for (int d = 1; d < 16; d <<= 1) { const int u = __shfl_up(v2, d); if (t >= d) v2 += u; }
        wexc[t] = v2 - orig;
    }
    __syncthreads();
    const int base = wexc[wave] + (v - sum);
    #pragma unroll
    for (int k = 0; k < CPT; ++k) {
        cell_start[t * CPT + k] = base + loc[k];
        cell_cnt[t * CPT + k] = 0;            // reset -> scatter cursors
    }
    if (t == 1023) cell_start[NCELLS_PAD] = base + sum;
    __syncthreads();
    if (t < 64) {
        const int o = blk_gen[t];
        int s = o;
        #pragma unroll
        for (int d = 1; d < 64; d <<= 1) { const int u = __shfl_up(s, d); if (t >= d) s += u; }
        blk_goff[t] = s - o;
        if (t == 63) { counts[1] = s; counts[0] = N_ATOMS - s; }
    }
}

__global__ __launch_bounds__(NTHR)
void k3_scatter(const float* __restrict__ X,
                const unsigned long long* __restrict__ flags,
                const int* __restrict__ blk_goff,
                const int* __restrict__ cell_start,
                int* __restrict__ cell_cur,
                float4* __restrict__ ctx4s,
                int* __restrict__ genidx)
{
    const int t = threadIdx.x;
    const int wave = t >> 6, lane = t & 63;
    const int i = blockIdx.x * NTHR + t;
    const unsigned long long fw = flags[blockIdx.x * 4 + wave];
    const bool g = (fw >> lane) & 1ull;
    int og = blk_goff[blockIdx.x];
    int oc = blockIdx.x * NTHR - og;
    #pragma unroll
    for (int w = 0; w < 4; ++w) {
        if (w < wave) {
            const int p = __popcll(flags[blockIdx.x * 4 + w]);
            og += p; oc += 64 - p;
        }
    }
    const unsigned long long below = (1ull << lane) - 1ull;
    og += __popcll(fw & below);
    oc += __popcll((~fw) & below);
    if (g) {
        genidx[og] = i;
    } else {
        const float x = X[3 * i], y = X[3 * i + 1], z = X[3 * i + 2];
        float xn = x * x; xn += y * y; xn += z * z;
        const int cx = cell1(x), cy = cell1(y), cz = cell1(z);
        const int c = (cz * G + cy) * G + cx;
        const int pos = cell_start[c] + atomicAdd(&cell_cur[c], 1);
        ctx4s[pos] = make_float4(x, y, z, xn);
    }
}

__global__ __launch_bounds__(512)
void k4_search(const float* __restrict__ X,
               const float* __restrict__ cnoise,
               const int* __restrict__ counts,
               const int* __restrict__ cell_start,
               const float4* __restrict__ ctx4s,
               const int* __restrict__ genidx,
               float* __restrict__ out)
{
    const int n_gen = counts[1];
    const int wave = threadIdx.x >> 6, lane = threadIdx.x & 63;
    const int slot = (int)blockIdx.x * 8 + wave;
    if (slot >= n_gen) return;

    const int ai = genidx[slot];
    const float qx = X[3 * ai], qy = X[3 * ai + 1], qz = X[3 * ai + 2];
    float xnq = qx * qx; xnq += qy * qy; xnq += qz * qz;
    const int cqx = cell1(qx), cqy = cell1(qy), cqz = cell1(qz);

    float s1 = SINIT, s2 = SINIT, s3 = SINIT;
    int i1 = 0, i2 = 0, i3 = 0;

    // shells r<=1: 27-cell box, one cell per lane, 2-deep load pipeline
    if (lane < 27) {
        const int dx = lane % 3 - 1, dy = (lane / 3) % 3 - 1, dz = lane / 9 - 1;
        const int cx = cqx + dx, cy = cqy + dy, cz = cqz + dz;
        if ((unsigned)cx < G && (unsigned)cy < G && (unsigned)cz < G) {
            const int c = (cz * G + cy) * G + cx;
            const int p0 = cell_start[c], p1 = cell_start[c + 1];
            if (p0 < p1) {
                float4 cc = ctx4s[p0];
                for (int p = p0; p < p1; ++p) {
                    float4 nxt;
                    if (p + 1 < p1) nxt = ctx4s[p + 1];
                    const float dot = qx * cc.x + qy * cc.y + qz * cc.z;
                    const float sq = (xnq + cc.w) - 2.0f * dot;
                    ins3(sq, p, s1, s2, s3, i1, i2, i3);
                    cc = nxt;
                }
            }
        }
    }

    int r = 1;
    for (;;) {
        // wave-merged 3rd-best value for convergence (copies; lane state untouched)
        float m1 = s1, m2 = s2, m3 = s3;
        #pragma unroll
        for (int m = 1; m < 64; m <<= 1) {
            const float a = __shfl_xor(m1, m);
            const float b = __shfl_xor(m2, m);
            const float c = __shfl_xor(m3, m);
            ins3v(a, m1, m2, m3); ins3v(b, m1, m2, m3); ins3v(c, m1, m2, m3);
        }
        const float bnd = (float)(4 * r) * (float)(4 * r);
        if (m3 + 0.01f < bnd || r >= G) break;   // unsearched atoms >= 4r away (safe margin)
        ++r;
        const int B = 2 * r + 1, B2 = B * B, V = B2 * B;
        for (int u = lane; u < V; u += 64) {
            int dz = u / B2; const int rem = u - dz * B2;
            int dy = rem / B; int dx = rem - dy * B;
            dx -= r; dy -= r; dz -= r;
            const int ax = abs(dx), ay = abs(dy), az = abs(dz);
            if (max(ax, max(ay, az)) != r) continue;   // shell only
            const int cx = cqx + dx, cy = cqy + dy, cz = cqz + dz;
            if ((unsigned)cx >= G || (unsigned)cy >= G || (unsigned)cz >= G) continue;
            const int c = (cz * G + cy) * G + cx;
            const int p0 = cell_start[c], p1 = cell_start[c + 1];
            for (int p = p0; p < p1; ++p) {
                const float4 cc = ctx4s[p];
                const float dot = qx * cc.x + qy * cc.y + qz * cc.z;
                const float sq = (xnq + cc.w) - 2.0f * dot;
                ins3(sq, p, s1, s2, s3, i1, i2, i3);
            }
        }
    }

    // final full merge with indices (each candidate lives in exactly one lane)
    #pragma unroll
    for (int m = 1; m < 64; m <<= 1) {
        const float a = __shfl_xor(s1, m); const int ja = __shfl_xor(i1, m);
        const float b = __shfl_xor(s2, m); const int jb = __shfl_xor(i2, m);
        const float c = __shfl_xor(s3, m); const int jc = __shfl_xor(i3, m);
        ins3(a, ja, s1, s2, s3, i1, i2, i3);
        ins3(b, jb, s1, s2, s3, i1, i2, i3);
        ins3(c, jc, s1, s2, s3, i1, i2, i3);
    }

    if (lane == 0) {
        const float d1 = sqrtf(fmaxf(s1, 0.0f) + 1e-12f);
        const float d2 = sqrtf(fmaxf(s2, 0.0f) + 1e-12f);
        const float d3 = sqrtf(fmaxf(s3, 0.0f) + 1e-12f);
        float w1 = 1.0f / (d1 + 1e-8f);
        float w2 = 1.0f / (d2 + 1e-8f);
        float w3 = 1.0f / (d3 + 1e-8f);
        float wsum = w1 + w2;
        wsum += w3;
        w1 /= wsum; w2 /= wsum; w3 /= wsum;
        const float4 c1 = ctx4s[i1];
        const float4 c2 = ctx4s[i2];
        const float4 c3 = ctx4s[i3];
        float cxo = w1 * c1.x + w2 * c2.x; cxo += w3 * c3.x;
        float cyo = w1 * c1.y + w2 * c2.y; cyo += w3 * c3.y;
        float czo = w1 * c1.z + w2 * c2.z; czo += w3 * c3.z;
        out[3 * ai + 0] = cxo + 0.5f * cnoise[3 * ai + 0];
        out[3 * ai + 1] = cyo + 0.5f * cnoise[3 * ai + 1];
        out[3 * ai + 2] = czo + 0.5f * cnoise[3 * ai + 2];
    }
}

extern "C" void kernel_launch(void* const* d_in, const int* in_sizes, int n_in,
                              void* d_out, int out_size, void* d_ws, size_t ws_size,
                              hipStream_t stream) {
    const float* X          = (const float*)d_in[0];
    const float* base_noise = (const float*)d_in[1];
    const float* cnoise     = (const float*)d_in[2];
    const int*   block_ids  = (const int*)d_in[3];
    const unsigned int* gmask = (const unsigned int*)d_in[4];
    float* out = (float*)d_out;

    char* ws = (char*)d_ws;
    int*    counts     = (int*)(ws + OFF_COUNTS);
    int*    blk_gen    = (int*)(ws + OFF_BLKGEN);
    int*    blk_goff   = (int*)(ws + OFF_BLKGOFF);
    unsigned long long* flags = (unsigned long long*)(ws + OFF_FLAGS);
    int*    cell_cnt   = (int*)(ws + OFF_CNT);
    int*    cell_start = (int*)(ws + OFF_START);
    int*    genidx     = (int*)(ws + OFF_GENIDX);
    float4* ctx4s      = (float4*)(ws + OFF_CTX4);

    hipMemsetAsync(ws + OFF_CNT, 0, NCELLS_PAD * sizeof(int), stream);
    k1_classify<<<NBLK, NTHR, 0, stream>>>(X, block_ids, gmask, base_noise,
                                           out, flags, blk_gen, cell_cnt);
    k2_scan<<<1, 1024, 0, stream>>>(cell_cnt, cell_start, blk_gen, blk_goff, counts);
    k3_scatter<<<NBLK, NTHR, 0, stream>>>(X, flags, blk_goff, cell_start,
                                          cell_cnt, ctx4s, genidx);
    k4_search<<<N_ATOMS / 8, 512, 0, stream>>>(X, cnoise, counts, cell_start,
                                               ctx4s, genidx, out);
}